// Round 6
// baseline (55.004 us; speedup 1.0000x reference)
//
#include <hip/hip_runtime.h>
#include <hip/hip_cooperative_groups.h>

namespace cg = cooperative_groups;

#define H 16
#define L 4096
#define D 64
#define R 128
#define CHUNK 128
#define NC 32
#define HL (H * L)
#define HN (H * NC)
#define C2 64
#define NC2 64
#define HN2 (H * NC2)
#define EPS 1e-10f
#define XS_SCALE 0.125f                    // sqrt(0.125)/64^0.25 == 1/8 exactly
#define PHI_SCALE 0.08838834764831845f     // 1/sqrt(128)

typedef __attribute__((ext_vector_type(8))) short bf8;     // 8 bf16
typedef __attribute__((ext_vector_type(4))) short bf4;     // 4 bf16
typedef __attribute__((ext_vector_type(16))) float facc16; // 32x32 MFMA acc

__device__ __forceinline__ unsigned short f2b(float f) {
    unsigned u = __float_as_uint(f);
    return (unsigned short)((u + 0x7fffu + ((u >> 16) & 1u)) >> 16);  // RNE
}
__device__ __forceinline__ float b2f(unsigned short s) {
    return __uint_as_float(((unsigned)s) << 16);
}

// ======================= prep: vTg (swizzled bf16) + Wtg (linear bf16) ======
__global__ __launch_bounds__(256) void prep_kernel(const float* __restrict__ v,
                                                   const float* __restrict__ W,
                                                   unsigned short* __restrict__ vTg,
                                                   unsigned short* __restrict__ Wtg) {
    const int tid = threadIdx.x;
    if (blockIdx.x < HN2) {
        __shared__ float vl[64 * 65];
        const int hn = blockIdx.x;
        const float* vg = v + (size_t)hn * C2 * D;
        for (int i = tid; i < 1024; i += 256) {
            int c = i >> 4, d0 = (i & 15) * 4;
            float4 t = *(const float4*)(vg + c * 64 + d0);
            vl[c * 65 + d0] = t.x; vl[c * 65 + d0 + 1] = t.y;
            vl[c * 65 + d0 + 2] = t.z; vl[c * 65 + d0 + 3] = t.w;
        }
        __syncthreads();
        unsigned short* o = vTg + (size_t)hn * 4096;
        for (int i = tid; i < 4096; i += 256) {     // o[(d*64+c)^((d&7)<<3)] = v[c][d]
            int d = i >> 6;
            int c = (i & 63) ^ ((d & 7) << 3);
            o[i] = f2b(vl[c * 65 + d]);
        }
    } else {
        __shared__ float wl[64 * 130];
        for (int i = tid; i < 8192; i += 256) {     // W[d][r] coalesced
            int d = i >> 7, r = i & 127;
            wl[d * 130 + r] = W[i];
        }
        __syncthreads();
        for (int i = tid; i < 8192; i += 256) {     // Wtg[r*64+d] = W[d][r]
            int r = i >> 6, d = i & 63;
            Wtg[i] = f2b(wl[d * 130 + r]);
        }
    }
}

// ======================= fused64: CHUNK=64, 1024 blocks, 40KB LDS ===========
__device__ __forceinline__ void p2_64(unsigned short* __restrict__ skvTp,
                                      const float* __restrict__ zk,
                                      unsigned short* __restrict__ zkp,
                                      int bid, int tid) {
    int g = bid * 256 + tid;                        // [0, 262144)
    if (g < 131072) {                               // H*D*R columns, in-place scan
        int h = g >> 13, dr = g & 8191;
        unsigned short* p = skvTp + (size_t)h * NC2 * 8192 + dr;
        float run = 0.f;
        #pragma unroll
        for (int n = 0; n < NC2; ++n) {
            float t = b2f(p[(size_t)n * 8192]);
            p[(size_t)n * 8192] = f2b(run);
            run += t;
        }
    } else if (g < 133120) {                        // H*R zk columns
        int g2 = g - 131072;
        int h = g2 >> 7, r = g2 & 127;
        const float* pz = zk + (size_t)h * NC2 * 128 + r;
        unsigned short* oz = zkp + (size_t)h * NC2 * 128 + r;
        float run = 0.f;
        #pragma unroll
        for (int n = 0; n < NC2; ++n) {
            float t = pz[n * 128];
            oz[n * 128] = f2b(run);
            run += t;
        }
    }
}

__global__ __launch_bounds__(256, 4) void fused64(
    const float* __restrict__ q, const float* __restrict__ k,
    const unsigned short* __restrict__ vTg, const unsigned short* __restrict__ Wtg,
    unsigned short* __restrict__ skvTp,   // [HN2][D][R] bf16: local sums -> excl prefix
    float* __restrict__ zk,               // [HN2][R] f32
    unsigned short* __restrict__ zkp,     // [HN2][R] bf16 excl prefix
    float* __restrict__ out)
{
    __shared__ __align__(16) unsigned short bufA[8192];  // pk[c][r] -> A[l][s]
    __shared__ __align__(16) unsigned short bufB[4096];  // xs[row][d] -> vT[d][c]
    __shared__ __align__(16) unsigned short bufC[8192];  // pq[c][r] -> pkT[r][c] -> svl[d][r]
    const int tid = threadIdx.x, hn = blockIdx.x;
    const int lane = tid & 63, wave = tid >> 6, lo = lane & 31, hi = lane >> 5;
    const int rg = wave & 1;            // row-group (rows rg*32..rg*32+31)
    const int ch = wave >> 1;           // col-half
    const size_t cbase = (size_t)hn * C2 * D;

    // ---------------- phi_q ----------------
    for (int i = tid; i < 1024; i += 256) {          // xs_q -> bufB (packed b64)
        int row = i >> 4, d0 = (i & 15) * 4;
        float4 vv = *(const float4*)(q + cbase + row * 64 + d0);
        unsigned* p = (unsigned*)&bufB[(unsigned)((row * 64 + d0) ^ ((row & 7) << 3))];
        p[0] = (unsigned)f2b(vv.x * XS_SCALE) | ((unsigned)f2b(vv.y * XS_SCALE) << 16);
        p[1] = (unsigned)f2b(vv.z * XS_SCALE) | ((unsigned)f2b(vv.w * XS_SCALE) << 16);
    }
    __syncthreads();
    {
        bf8 af[4];
        float ssq = 0.f;
        #pragma unroll
        for (int s = 0; s < 4; ++s) {
            af[s] = *(const bf8*)&bufB[(unsigned)(((rg * 32 + lo) * 64 + 16 * s + 8 * hi) ^ ((lo & 7) << 3))];
            #pragma unroll
            for (int e = 0; e < 8; ++e) { float t = b2f((unsigned short)af[s][e]); ssq += t * t; }
        }
        ssq += __shfl_xor(ssq, 32); ssq *= 0.5f;
        float sqrow[16];
        #pragma unroll
        for (int reg = 0; reg < 16; ++reg)
            sqrow[reg] = __shfl(ssq, (reg & 3) + 8 * (reg >> 2) + 4 * hi);

        facc16 acc[2];
        #pragma unroll
        for (int t = 0; t < 2; ++t)
            #pragma unroll
            for (int e = 0; e < 16; ++e) acc[t][e] = 0.f;
        #pragma unroll
        for (int s = 0; s < 4; ++s)
            #pragma unroll
            for (int t = 0; t < 2; ++t) {
                const bf8 b = *(const bf8*)(Wtg + ((2 * ch + t) * 32 + lo) * 64 + 16 * s + 8 * hi);
                acc[t] = __builtin_amdgcn_mfma_f32_32x32x16_bf16(af[s], b, acc[t], 0, 0, 0);
            }
        #pragma unroll
        for (int t = 0; t < 2; ++t)
            #pragma unroll
            for (int reg = 0; reg < 16; ++reg) {
                int row = rg * 32 + (reg & 3) + 8 * (reg >> 2) + 4 * hi;
                int col = (2 * ch + t) * 32 + lo;
                bufC[(unsigned)((row * 128 + col) ^ ((row & 15) << 3))] =
                    f2b(__expf(acc[t][reg] - sqrow[reg]) * PHI_SCALE);
            }
    }
    __syncthreads();

    bf8 qf[8];                                       // pq strip in regs (all phases)
    #pragma unroll
    for (int s = 0; s < 8; ++s)
        qf[s] = *(const bf8*)&bufC[(unsigned)(((rg * 32 + lo) * 128 + 16 * s + 8 * hi) ^ ((lo & 15) << 3))];

    // ---------------- phi_k ----------------
    for (int i = tid; i < 1024; i += 256) {          // xs_k -> bufB
        int row = i >> 4, d0 = (i & 15) * 4;
        float4 vv = *(const float4*)(k + cbase + row * 64 + d0);
        unsigned* p = (unsigned*)&bufB[(unsigned)((row * 64 + d0) ^ ((row & 7) << 3))];
        p[0] = (unsigned)f2b(vv.x * XS_SCALE) | ((unsigned)f2b(vv.y * XS_SCALE) << 16);
        p[1] = (unsigned)f2b(vv.z * XS_SCALE) | ((unsigned)f2b(vv.w * XS_SCALE) << 16);
    }
    __syncthreads();
    {
        bf8 af[4];
        float ssq = 0.f;
        #pragma unroll
        for (int s = 0; s < 4; ++s) {
            af[s] = *(const bf8*)&bufB[(unsigned)(((rg * 32 + lo) * 64 + 16 * s + 8 * hi) ^ ((lo & 7) << 3))];
            #pragma unroll
            for (int e = 0; e < 8; ++e) { float t = b2f((unsigned short)af[s][e]); ssq += t * t; }
        }
        ssq += __shfl_xor(ssq, 32); ssq *= 0.5f;
        float sqrow[16];
        #pragma unroll
        for (int reg = 0; reg < 16; ++reg)
            sqrow[reg] = __shfl(ssq, (reg & 3) + 8 * (reg >> 2) + 4 * hi);

        facc16 acc[2];
        #pragma unroll
        for (int t = 0; t < 2; ++t)
            #pragma unroll
            for (int e = 0; e < 16; ++e) acc[t][e] = 0.f;
        #pragma unroll
        for (int s = 0; s < 4; ++s)
            #pragma unroll
            for (int t = 0; t < 2; ++t) {
                const bf8 b = *(const bf8*)(Wtg + ((2 * ch + t) * 32 + lo) * 64 + 16 * s + 8 * hi);
                acc[t] = __builtin_amdgcn_mfma_f32_32x32x16_bf16(af[s], b, acc[t], 0, 0, 0);
            }
        // epilogue: pk[c][r] -> bufA (scalar), pkT[r][c] -> bufC (packed b64)
        #pragma unroll
        for (int t = 0; t < 2; ++t) {
            int colr = (2 * ch + t) * 32 + lo;
            #pragma unroll
            for (int g = 0; g < 4; ++g) {
                int c0 = rg * 32 + 8 * g + 4 * hi;
                bf4 pk4;
                #pragma unroll
                for (int e = 0; e < 4; ++e) {
                    unsigned short b = f2b(__expf(acc[t][4 * g + e] - sqrow[4 * g + e]) * PHI_SCALE);
                    pk4[e] = (short)b;
                    bufA[(unsigned)(((c0 + e) * 128 + colr) ^ (((c0 + e) & 15) << 3))] = b;
                }
                *(bf4*)&bufC[(unsigned)((colr * 64 + c0) ^ ((colr & 7) << 3))] = pk4;
            }
        }
    }
    __syncthreads();                                 // pk, pkT ready; xs_k dead

    // ---------------- vT copy + zk ----------------
    for (int i = tid; i < 512; i += 256)             // vTg (swizzle baked) -> bufB
        *(bf8*)&bufB[i * 8] = *(const bf8*)(vTg + (size_t)hn * 4096 + i * 8);
    if (tid < 128) {                                 // zk[r] = rowsum pkT
        float s = 0.f;
        #pragma unroll
        for (int j = 0; j < 8; ++j) {
            bf8 a8 = *(const bf8*)&bufC[(unsigned)((tid * 64 + 8 * j) ^ ((tid & 7) << 3))];
            #pragma unroll
            for (int e = 0; e < 8; ++e) s += b2f((unsigned short)a8[e]);
        }
        zk[(size_t)hn * 128 + tid] = s;
    }
    __syncthreads();

    // ---------------- skv: skvT[d][r] = sum_c vT[d][c] pkT[r][c] ------------
    {
        facc16 acs[2];
        #pragma unroll
        for (int t = 0; t < 2; ++t)
            #pragma unroll
            for (int e = 0; e < 16; ++e) acs[t][e] = 0.f;
        #pragma unroll
        for (int s = 0; s < 4; ++s) {
            const bf8 a = *(const bf8*)&bufB[(unsigned)((((rg) * 32 + lo) * 64 + 16 * s + 8 * hi) ^ ((lo & 7) << 3))];
            #pragma unroll
            for (int t = 0; t < 2; ++t) {
                const bf8 b = *(const bf8*)&bufC[(unsigned)((((2 * ch + t) * 32 + lo) * 64 + 16 * s + 8 * hi) ^ ((lo & 7) << 3))];
                acs[t] = __builtin_amdgcn_mfma_f32_32x32x16_bf16(a, b, acs[t], 0, 0, 0);
            }
        }
        unsigned short* sg = skvTp + (size_t)hn * 8192;
        #pragma unroll
        for (int t = 0; t < 2; ++t)
            #pragma unroll
            for (int reg = 0; reg < 16; ++reg) {
                int d = rg * 32 + (reg & 3) + 8 * (reg >> 2) + 4 * hi;
                int r = (2 * ch + t) * 32 + lo;
                sg[d * 128 + r] = f2b(acs[t][reg]);
            }
    }
    __threadfence();
    cg::this_grid().sync();

    // ---------------- phase 2: exclusive scans ----------------
    p2_64(skvTp, zk, zkp, hn, tid);
    __threadfence();
    cg::this_grid().sync();
    __threadfence();

    // ---------------- phase 3 ----------------
    for (int i = tid; i < 512; i += 256) {           // svl -> bufC ([d][r], &15 swz)
        bf8 t8 = *(const bf8*)(skvTp + (size_t)hn * 8192 + i * 8);
        int d = i >> 4, r0 = (i & 15) * 8;
        *(bf8*)&bufC[(unsigned)((d * 128 + r0) ^ ((d & 15) << 3))] = t8;
    }
    facc16 ac1;                                      // GEMM1: A = pq.pk^T
    #pragma unroll
    for (int e = 0; e < 16; ++e) ac1[e] = 0.f;
    #pragma unroll
    for (int s = 0; s < 8; ++s) {
        const bf8 b = *(const bf8*)&bufA[(unsigned)(((ch * 32 + lo) * 128 + 16 * s + 8 * hi) ^ ((lo & 15) << 3))];
        ac1 = __builtin_amdgcn_mfma_f32_32x32x16_bf16(qf[s], b, ac1, 0, 0, 0);
    }
    __syncthreads();                                 // pk reads + svl staging done

    #pragma unroll
    for (int reg = 0; reg < 16; ++reg) {             // masked A -> bufA [l][s]
        int row = rg * 32 + (reg & 3) + 8 * (reg >> 2) + 4 * hi;
        int sc = ch * 32 + lo;
        bufA[(unsigned)((row * 64 + sc) ^ ((row & 7) << 3))] = f2b(sc < row ? ac1[reg] : 0.f);
    }
    __syncthreads();

    facc16 an, ad;
    #pragma unroll
    for (int e = 0; e < 16; ++e) { an[e] = 0.f; ad[e] = 0.f; }
    bf8 onesf, zf[8];
    #pragma unroll
    for (int e = 0; e < 8; ++e) onesf[e] = (lo == 0) ? (short)0x3F80 : (short)0;
    #pragma unroll
    for (int s = 0; s < 8; ++s)
        #pragma unroll
        for (int e = 0; e < 8; ++e) zf[s][e] = 0;
    if (lo == 0) {
        #pragma unroll
        for (int s = 0; s < 8; ++s)
            zf[s] = *(const bf8*)(zkp + (size_t)hn * 128 + 16 * s + 8 * hi);
    }
    #pragma unroll
    for (int s = 0; s < 4; ++s) {                    // pass A: k = c
        const bf8 a = *(const bf8*)&bufA[(unsigned)(((rg * 32 + lo) * 64 + 16 * s + 8 * hi) ^ ((lo & 7) << 3))];
        const bf8 b = *(const bf8*)&bufB[(unsigned)(((ch * 32 + lo) * 64 + 16 * s + 8 * hi) ^ ((lo & 7) << 3))];
        an = __builtin_amdgcn_mfma_f32_32x32x16_bf16(a, b, an, 0, 0, 0);
        ad = __builtin_amdgcn_mfma_f32_32x32x16_bf16(a, onesf, ad, 0, 0, 0);
    }
    #pragma unroll
    for (int s = 0; s < 8; ++s) {                    // pass B: k = r
        const bf8 b = *(const bf8*)&bufC[(unsigned)(((ch * 32 + lo) * 128 + 16 * s + 8 * hi) ^ ((lo & 15) << 3))];
        an = __builtin_amdgcn_mfma_f32_32x32x16_bf16(qf[s], b, an, 0, 0, 0);
        ad = __builtin_amdgcn_mfma_f32_32x32x16_bf16(qf[s], zf[s], ad, 0, 0, 0);
    }
    float* og = out + (size_t)hn * C2 * D;
    #pragma unroll
    for (int reg = 0; reg < 16; ++reg) {
        int row = rg * 32 + (reg & 3) + 8 * (reg >> 2) + 4 * hi;
        float dv = __shfl(ad[reg], lane & 32);
        og[row * 64 + ch * 32 + lo] = an[reg] / (dv + EPS);
    }
}

// ======================= R5 fallback (CHUNK=128) ============================
template<bool DUMP>
__device__ __forceinline__ void phase1(
    const float* __restrict__ q, const float* __restrict__ k,
    const float* __restrict__ v, const float* __restrict__ W,
    unsigned short* bufA, unsigned short* bufB, unsigned short* bufC,
    float* __restrict__ stage, float* __restrict__ zk,
    unsigned short* __restrict__ pqd, unsigned short* __restrict__ pkd,
    unsigned short* __restrict__ vTd, bf8* qf, int hn, int tid)
{
    unsigned short* Wt = bufC;
    unsigned short* xs = bufC + 8192;
    float* sq = (float*)bufB;
    const int lane = tid & 63, wave = tid >> 6, lo = lane & 31, hi = lane >> 5;
    const int l0 = wave * 32;
    const size_t cbase = (size_t)hn * CHUNK * D;

    for (int i = tid; i < 8192; i += 256) {
        int r = i & 127, d = i >> 7;
        Wt[(unsigned)((r * 64 + d) ^ ((r & 7) << 3))] = f2b(W[d * 128 + r]);
    }
    for (int i = tid; i < 2048; i += 256) {
        int row = i >> 4, d0 = (i & 15) * 4;
        float4 vv = *(const float4*)(q + cbase + row * 64 + d0);
        float a0 = vv.x * XS_SCALE, a1 = vv.y * XS_SCALE;
        float a2 = vv.z * XS_SCALE, a3 = vv.w * XS_SCALE;
        float ss = a0 * a0 + a1 * a1 + a2 * a2 + a3 * a3;
        ss += __shfl_xor(ss, 1); ss += __shfl_xor(ss, 2);
        ss += __shfl_xor(ss, 4); ss += __shfl_xor(ss, 8);
        if ((tid & 15) == 0) sq[row] = 0.5f * ss;
        unsigned idx = (unsigned)((row * 64 + d0) ^ ((row & 7) << 3));
        unsigned* p = (unsigned*)&xs[idx];
        p[0] = (unsigned)f2b(a0) | ((unsigned)f2b(a1) << 16);
        p[1] = (unsigned)f2b(a2) | ((unsigned)f2b(a3) << 16);
    }
    __syncthreads();
    {
        facc16 acc[4];
        #pragma unroll
        for (int t = 0; t < 4; ++t)
            #pragma unroll
            for (int e = 0; e < 16; ++e) acc[t][e] = 0.f;
        #pragma unroll
        for (int s = 0; s < 4; ++s) {
            const bf8 a = *(const bf8*)&xs[(unsigned)(((l0 + lo) * 64 + 16 * s + 8 * hi) ^ ((lo & 7) << 3))];
            #pragma unroll
            for (int t = 0; t < 4; ++t) {
                const bf8 b = *(const bf8*)&Wt[(unsigned)(((t * 32 + lo) * 64 + 16 * s + 8 * hi) ^ ((lo & 7) << 3))];
                acc[t] = __builtin_amdgcn_mfma_f32_32x32x16_bf16(a, b, acc[t], 0, 0, 0);
            }
        }
        #pragma unroll
        for (int t = 0; t < 4; ++t)
            #pragma unroll
            for (int reg = 0; reg < 16; ++reg) {
                int row = l0 + (reg & 3) + 8 * (reg >> 2) + 4 * hi;
                int col = t * 32 + lo;
                bufA[(unsigned)((row * 128 + col) ^ ((row & 7) << 3))] =
                    f2b(__expf(acc[t][reg] - sq[row]) * PHI_SCALE);
            }
    }
    __syncthreads();
    #pragma unroll
    for (int s = 0; s < 8; ++s)
        qf[s] = *(const bf8*)&bufA[(unsigned)(((l0 + lo) * 128 + 16 * s + 8 * hi) ^ ((lo & 7) << 3))];
    if constexpr (DUMP) {
        unsigned short* pg = pqd + (size_t)hn * CHUNK * R;
        for (int i = tid; i < 2048; i += 256) {
            int c = i >> 4, rb = (i & 15) * 8;
            *(bf8*)(pg + c * 128 + rb) = *(const bf8*)&bufA[(unsigned)((c * 128 + rb) ^ ((c & 7) << 3))];
        }
    }
    for (int i = tid; i < 2048; i += 256) {
        int row = i >> 4, d0 = (i & 15) * 4;
        float4 vv = *(const float4*)(k + cbase + row * 64 + d0);
        float a0 = vv.x * XS_SCALE, a1 = vv.y * XS_SCALE;
        float a2 = vv.z * XS_SCALE, a3 = vv.w * XS_SCALE;
        float ss = a0 * a0 + a1 * a1 + a2 * a2 + a3 * a3;
        ss += __shfl_xor(ss, 1); ss += __shfl_xor(ss, 2);
        ss += __shfl_xor(ss, 4); ss += __shfl_xor(ss, 8);
        if ((tid & 15) == 0) sq[row] = 0.5f * ss;
        unsigned idx = (unsigned)((row * 64 + d0) ^ ((row & 7) << 3));
        unsigned* p = (unsigned*)&xs[idx];
        p[0] = (unsigned)f2b(a0) | ((unsigned)f2b(a1) << 16);
        p[1] = (unsigned)f2b(a2) | ((unsigned)f2b(a3) << 16);
    }
    __syncthreads();
    facc16 acck[4];
    #pragma unroll
    for (int t = 0; t < 4; ++t)
        #pragma unroll
        for (int e = 0; e < 16; ++e) acck[t][e] = 0.f;
    #pragma unroll
    for (int s = 0; s < 4; ++s) {
        const bf8 a = *(const bf8*)&xs[(unsigned)(((l0 + lo) * 64 + 16 * s + 8 * hi) ^ ((lo & 7) << 3))];
        #pragma unroll
        for (int t = 0; t < 4; ++t) {
            const bf8 b = *(const bf8*)&Wt[(unsigned)(((t * 32 + lo) * 64 + 16 * s + 8 * hi) ^ ((lo & 7) << 3))];
            acck[t] = __builtin_amdgcn_mfma_f32_32x32x16_bf16(a, b, acck[t], 0, 0, 0);
        }
    }
    __syncthreads();
    #pragma unroll
    for (int t = 0; t < 4; ++t) {
        int colr = t * 32 + lo;
        #pragma unroll
        for (int g = 0; g < 4; ++g) {
            int c0 = l0 + 8 * g + 4 * hi;
            bf4 pk4;
            #pragma unroll
            for (int e = 0; e < 4; ++e) {
                unsigned short b = f2b(__expf(acck[t][4 * g + e] - sq[c0 + e]) * PHI_SCALE);
                pk4[e] = (short)b;
                bufA[(unsigned)(((c0 + e) * 128 + colr) ^ (((c0 + e) & 7) << 3))] = b;
            }
            *(bf4*)&bufC[(unsigned)((colr * 128 + c0) ^ ((colr & 7) << 3))] = pk4;
        }
    }
    __syncthreads();
    for (int i = tid; i < 8192; i += 256) {
        int d = i & 63, c = i >> 6;
        bufB[(unsigned)((d * 128 + c) ^ ((d & 7) << 3))] = f2b(v[cbase + c * 64 + d]);
    }
    if (tid < 128) {
        float s = 0.f;
        #pragma unroll
        for (int j = 0; j < 16; ++j) {
            bf8 a8 = *(const bf8*)&bufC[(unsigned)((tid * 128 + 8 * j) ^ ((tid & 7) << 3))];
            #pragma unroll
            for (int e = 0; e < 8; ++e) s += b2f((unsigned short)a8[e]);
        }
        zk[(size_t)hn * 128 + tid] = s;
    }
    if constexpr (DUMP) {
        unsigned short* pg = pkd + (size_t)hn * CHUNK * R;
        for (int i = tid; i < 2048; i += 256) {
            int c = i >> 4, rb = (i & 15) * 8;
            *(bf8*)(pg + c * 128 + rb) = *(const bf8*)&bufA[(unsigned)((c * 128 + rb) ^ ((c & 7) << 3))];
        }
    }
    __syncthreads();
    if constexpr (DUMP) {
        unsigned short* vg2 = vTd + (size_t)hn * D * CHUNK;
        for (int i = tid; i < 1024; i += 256) {
            int d = i >> 4, c0 = (i & 15) * 8;
            *(bf8*)(vg2 + d * 128 + c0) = *(const bf8*)&bufB[(unsigned)((d * 128 + c0) ^ ((d & 7) << 3))];
        }
    }
    {
        facc16 accs[2];
        #pragma unroll
        for (int t = 0; t < 2; ++t)
            #pragma unroll
            for (int e = 0; e < 16; ++e) accs[t][e] = 0.f;
        #pragma unroll
        for (int s = 0; s < 8; ++s) {
            const bf8 b = *(const bf8*)&bufC[(unsigned)(((wave * 32 + lo) * 128 + 16 * s + 8 * hi) ^ ((lo & 7) << 3))];
            #pragma unroll
            for (int db = 0; db < 2; ++db) {
                const bf8 a = *(const bf8*)&bufB[(unsigned)(((db * 32 + lo) * 128 + 16 * s + 8 * hi) ^ ((lo & 7) << 3))];
                accs[db] = __builtin_amdgcn_mfma_f32_32x32x16_bf16(a, b, accs[db], 0, 0, 0);
            }
        }
        float* sg = stage + (size_t)hn * D * R;
        #pragma unroll
        for (int db = 0; db < 2; ++db)
            #pragma unroll
            for (int reg = 0; reg < 16; ++reg) {
                int row = db * 32 + (reg & 3) + 8 * (reg >> 2) + 4 * hi;
                sg[row * 128 + wave * 32 + lo] = accs[db][reg];
            }
    }
}

__device__ __forceinline__ void phase2(const float* __restrict__ stage,
                                       unsigned short* __restrict__ skvTp,
                                       const float* __restrict__ zk,
                                       unsigned short* __restrict__ zkp,
                                       int bid, int tid)
{
    int g = bid * 256 + tid;
    int h2 = g >> 13, dr = g & 8191;
    const float* p = stage + (size_t)h2 * NC * 8192 + dr;
    unsigned short* o = skvTp + (size_t)h2 * NC * 8192 + dr;
    float run = 0.f;
    #pragma unroll
    for (int n = 0; n < NC; ++n) {
        float t = p[(size_t)n * 8192];
        o[(size_t)n * 8192] = f2b(run);
        run += t;
    }
    if (g < 2048) {
        int h3 = g >> 7, r = g & 127;
        const float* pz = zk + (size_t)h3 * NC * 128 + r;
        unsigned short* oz = zkp + (size_t)h3 * NC * 128 + r;
        float runz = 0.f;
        #pragma unroll
        for (int n = 0; n < NC; ++n) {
            float t2 = pz[n * 128];
            oz[n * 128] = f2b(runz);
            runz += t2;
        }
    }
}

__device__ __forceinline__ void phase3(
    unsigned short* bufA, unsigned short* bufB, unsigned short* bufC,
    const unsigned short* __restrict__ skvTp, const unsigned short* __restrict__ zkp,
    const bf8* qf, int hn, int tid, float* __restrict__ out)
{
    const int lane = tid & 63, wave = tid >> 6, lo = lane & 31, hi = lane >> 5;
    const int l0 = wave * 32;
    __syncthreads();
    const unsigned short* svg = skvTp + (size_t)hn * D * R;
    for (int i = tid; i < 1024; i += 256) {
        int d = i >> 4, r0 = (i & 15) * 8;
        *(bf8*)&bufC[(unsigned)((d * 128 + r0) ^ ((d & 7) << 3))] = *(const bf8*)(svg + d * 128 + r0);
    }
    bf8 zf[8], onesf;
    #pragma unroll
    for (int e = 0; e < 8; ++e) onesf[e] = (lo == 0) ? (short)0x3F80 : (short)0;
    #pragma unroll
    for (int s = 0; s < 8; ++s)
        #pragma unroll
        for (int e = 0; e < 8; ++e) zf[s][e] = 0;
    if (lo == 0) {
        #pragma unroll
        for (int s = 0; s < 8; ++s)
            zf[s] = *(const bf8*)(zkp + (size_t)hn * 128 + 16 * s + 8 * hi);
    }
    facc16 acc1[4];
    #pragma unroll
    for (int t = 0; t < 4; ++t)
        #pragma unroll
        for (int e = 0; e < 16; ++e) acc1[t][e] = 0.f;
    #pragma unroll
    for (int s = 0; s < 8; ++s)
        #pragma unroll
        for (int t = 0; t < 4; ++t) {
            const bf8 b = *(const bf8*)&bufA[(unsigned)(((t * 32 + lo) * 128 + 16 * s + 8 * hi) ^ ((lo & 7) << 3))];
            acc1[t] = __builtin_amdgcn_mfma_f32_32x32x16_bf16(qf[s], b, acc1[t], 0, 0, 0);
        }
    __syncthreads();
    #pragma unroll
    for (int t = 0; t < 4; ++t)
        #pragma unroll
        for (int reg = 0; reg < 16; ++reg) {
            int row = l0 + (reg & 3) + 8 * (reg >> 2) + 4 * hi;
            int sc = t * 32 + lo;
            bufA[(unsigned)((row * 128 + sc) ^ ((row & 7) << 3))] = f2b(sc < row ? acc1[t][reg] : 0.f);
        }
    __syncthreads();
    facc16 acc2[3];
    #pragma unroll
    for (int t = 0; t < 3; ++t)
        #pragma unroll
        for (int e = 0; e < 16; ++e) acc2[t][e] = 0.f;
    #pragma unroll
    for (int s = 0; s < 8; ++s) {
        const bf8 a = *(const bf8*)&bufA[(unsigned)(((l0 + lo) * 128 + 16 * s + 8 * hi) ^ ((lo & 7) << 3))];
        #pragma unroll
        for (int t = 0; t < 2; ++t) {
            const bf8 b = *(const bf8*)&bufB[(unsigned)(((t * 32 + lo) * 128 + 16 * s + 8 * hi) ^ ((lo & 7) << 3))];
            acc2[t] = __builtin_amdgcn_mfma_f32_32x32x16_bf16(a, b, acc2[t], 0, 0, 0);
        }
        acc2[2] = __builtin_amdgcn_mfma_f32_32x32x16_bf16(a, onesf, acc2[2], 0, 0, 0);
    }
    #pragma unroll
    for (int s = 0; s < 8; ++s) {
        #pragma unroll
        for (int t = 0; t < 2; ++t) {
            const bf8 b = *(const bf8*)&bufC[(unsigned)(((t * 32 + lo) * 128 + 16 * s + 8 * hi) ^ ((lo & 7) << 3))];
            acc2[t] = __builtin_amdgcn_mfma_f32_32x32x16_bf16(qf[s], b, acc2[t], 0, 0, 0);
        }
        acc2[2] = __builtin_amdgcn_mfma_f32_32x32x16_bf16(qf[s], zf[s], acc2[2], 0, 0, 0);
    }
    float* og = out + (size_t)hn * CHUNK * D;
    #pragma unroll
    for (int reg = 0; reg < 16; ++reg) {
        int row = l0 + (reg & 3) + 8 * (reg >> 2) + 4 * hi;
        float dv = __shfl(acc2[2][reg], lane & 32);
        float inv = 1.0f / (dv + EPS);
        og[row * 64 + lo]      = acc2[0][reg] * inv;
        og[row * 64 + 32 + lo] = acc2[1][reg] * inv;
    }
}

__global__ __launch_bounds__(256, 2) void fused_coop(
    const float* __restrict__ q, const float* __restrict__ k,
    const float* __restrict__ v, const float* __restrict__ W,
    unsigned short* __restrict__ skvTp, unsigned short* __restrict__ zkp,
    float* __restrict__ zk, float* __restrict__ out)
{
    __shared__ __align__(16) unsigned short LDSm[40960];
    unsigned short* bufA = LDSm;
    unsigned short* bufB = LDSm + 16384;
    unsigned short* bufC = LDSm + 24576;
    const int tid = threadIdx.x, hn = blockIdx.x;
    bf8 qf[8];
    phase1<false>(q, k, v, W, bufA, bufB, bufC, out, zk,
                  nullptr, nullptr, nullptr, qf, hn, tid);
    __threadfence();
    cg::this_grid().sync();
    phase2(out, skvTp, zk, zkp, hn, tid);
    __threadfence();
    cg::this_grid().sync();
    __threadfence();
    phase3(bufA, bufB, bufC, skvTp, zkp, qf, hn, tid, out);
}

__global__ __launch_bounds__(256, 2) void kA(
    const float* __restrict__ q, const float* __restrict__ k,
    const float* __restrict__ v, const float* __restrict__ W,
    float* __restrict__ stage, float* __restrict__ zk,
    unsigned short* __restrict__ pqd, unsigned short* __restrict__ pkd,
    unsigned short* __restrict__ vTd)
{
    __shared__ __align__(16) unsigned short LDSm[40960];
    bf8 qf[8];
    phase1<true>(q, k, v, W, LDSm, LDSm + 16384, LDSm + 24576, stage, zk,
                 pqd, pkd, vTd, qf, blockIdx.x, threadIdx.x);
}

__global__ __launch_bounds__(256) void kB(const float* __restrict__ stage,
                                          unsigned short* __restrict__ skvTp,
                                          const float* __restrict__ zk,
                                          unsigned short* __restrict__ zkp)
{
    phase2(stage, skvTp, zk, zkp, blockIdx.x, threadIdx.x);
}

__global__ __launch_bounds__(256, 2) void kC(
    const unsigned short* __restrict__ pq, const unsigned short* __restrict__ pk,
    const unsigned short* __restrict__ vT, const unsigned short* __restrict__ skvTp,
    const unsigned short* __restrict__ zkp, float* __restrict__ out)
{
    __shared__ __align__(16) unsigned short LDSm[32768];
    unsigned short* bufA = LDSm;
    unsigned short* bufB = LDSm + 16384;
    unsigned short* bufC = LDSm + 24576;
    const int tid = threadIdx.x, hn = blockIdx.x;
    const int lane = tid & 63, wave = tid >> 6, lo = lane & 31, hi = lane >> 5;
    const int l0 = wave * 32;
    bf8 qf[8];
    const unsigned short* pqg = pq + (size_t)hn * CHUNK * R;
    #pragma unroll
    for (int s = 0; s < 8; ++s)
        qf[s] = *(const bf8*)(pqg + (l0 + lo) * 128 + 16 * s + 8 * hi);
    const unsigned short* pkg = pk + (size_t)hn * CHUNK * R;
    for (int i = tid; i < 2048; i += 256) {
        int c = i >> 4, rb = (i & 15) * 8;
        *(bf8*)&bufA[(unsigned)((c * 128 + rb) ^ ((c & 7) << 3))] = *(const bf8*)(pkg + c * 128 + rb);
    }
    const unsigned short* vTg2 = vT + (size_t)hn * D * CHUNK;
    for (int i = tid; i < 1024; i += 256) {
        int d = i >> 4, c0 = (i & 15) * 8;
        *(bf8*)&bufB[(unsigned)((d * 128 + c0) ^ ((d & 7) << 3))] = *(const bf8*)(vTg2 + d * 128 + c0);
    }
    phase3(bufA, bufB, bufC, skvTp, zkp, qf, hn, tid, out);
}

// ---------------------------------------------------------------------------
extern "C" void kernel_launch(void* const* d_in, const int* in_sizes, int n_in,
                              void* d_out, int out_size, void* d_ws, size_t ws_size,
                              hipStream_t stream) {
    // setup_inputs order: {T, k, q, v, W}
    const float* k = (const float*)d_in[1];
    const float* q = (const float*)d_in[2];
    const float* v = (const float*)d_in[3];
    const float* W = (const float*)d_in[4];
    float* out = (float*)d_out;

    // fused64 ws layout: skvTp64 u16[HN2*8192] | zk64 f32[HN2*128] | zkp64 u16 | vTg u16 | Wtg u16
    unsigned short* skvTp64 = (unsigned short*)d_ws;
    float* zk64 = (float*)(skvTp64 + (size_t)HN2 * 8192);
    unsigned short* zkp64 = (unsigned short*)(zk64 + (size_t)HN2 * 128);
    unsigned short* vTg = zkp64 + (size_t)HN2 * 128;
    unsigned short* Wtg = vTg + (size_t)HN2 * 4096;

    // R5 ws layout (fallback, overlaps — paths are exclusive)
    unsigned short* skvTp = (unsigned short*)d_ws;
    unsigned short* zkp = skvTp + (size_t)HN * D * R;
    float* zk = (float*)(zkp + (size_t)HN * R);
    unsigned short* pq = (unsigned short*)(zk + (size_t)HN * R);
    unsigned short* pk = pq + (size_t)HL * R;
    unsigned short* vT = pk + (size_t)HL * R;

    int nb4 = 0;
    hipError_t qrc = hipOccupancyMaxActiveBlocksPerMultiprocessor(
        &nb4, (const void*)fused64, 256, 0);
    if (qrc == hipSuccess && nb4 >= 4) {
        prep_kernel<<<HN2 + 1, 256, 0, stream>>>(v, W, vTg, Wtg);
        void* kargs[8] = {(void*)&q, (void*)&k, (void*)&vTg, (void*)&Wtg,
                          (void*)&skvTp64, (void*)&zk64, (void*)&zkp64, (void*)&out};
        hipError_t rc = hipLaunchCooperativeKernel((const void*)fused64,
                                                   dim3(HN2), dim3(256), kargs, 0, stream);
        if (rc == hipSuccess) return;
        (void)hipGetLastError();
    }
    int nb2 = 0;
    qrc = hipOccupancyMaxActiveBlocksPerMultiprocessor(
        &nb2, (const void*)fused_coop, 256, 0);
    if (qrc == hipSuccess && nb2 >= 2) {
        void* kargs[8] = {(void*)&q, (void*)&k, (void*)&v, (void*)&W,
                          (void*)&skvTp, (void*)&zkp, (void*)&zk, (void*)&out};
        hipError_t rc = hipLaunchCooperativeKernel((const void*)fused_coop,
                                                   dim3(HN), dim3(256), kargs, 0, stream);
        if (rc == hipSuccess) return;
        (void)hipGetLastError();
    }
    kA<<<HN, 256, 0, stream>>>(q, k, v, W, out, zk, pq, pk, vT);
    kB<<<HN, 256, 0, stream>>>(out, skvTp, zk, zkp);
    kC<<<HN, 256, 0, stream>>>(pq, pk, vT, skvTp, zkp, out);
}